// Round 2
// baseline (993.132 us; speedup 1.0000x reference)
//
#include <hip/hip_runtime.h>
#include <hip/hip_bf16.h>

// Problem: out[b, n*128+o] = sum_m x[b, n*128+m] * softmax_m(c[n, m, o])
// B=2048, N_BLOCKS=512, BLOCK_IN=BLOCK_OUT=128, LAYER=65536.
// Memory-bound: ~1.04 GB mandatory traffic (x 512MB + out 512MB + w 16MB)
// -> ~166us floor @6.3TB/s. Bench dur_us also contains harness re-poison
// fills (~2x345us/iter, confirmed identical across rounds) -> ~690us floor
// we cannot touch. Controllable budget: gemm (~215us at baseline) + softmax
// (~10us).
//
// R1 lesson: register-direct A loads (row=lane&31 private) scatter 16B
// requests across 32 rows x 256KB stride -> uncoalesced, +50us. The LDS
// x-stage IS the transpose between coalesced HBM reads and the MFMA
// A-fragment layout. Keep it.
// R2 change: drop the *w* LDS staging instead (w is 32KB/block, L1/L2-hot,
// shared by 16 consecutive WGs) -> LDS 64KB->32KB -> 3 WGs/CU, and the
// barrier no longer waits on w.

#define N_BLOCKS 512
#define BI 128
#define BO 128
#define LAYER 65536
#define BATCH 2048

typedef __bf16 bf16x4_t __attribute__((ext_vector_type(4)));
typedef __bf16 bf16x8_t __attribute__((ext_vector_type(8)));
typedef float floatx16_t __attribute__((ext_vector_type(16)));

// ---------------------------------------------------------------------------
// Kernel 1: column softmax over m of c[n][m][o], write TRANSPOSED bf16
// w[n][o][m] so that K (=m) is contiguous for the GEMM's B-fragment reads.
// Wave-per-column, shuffle reductions. ~10us, not the bottleneck; unchanged.
// ---------------------------------------------------------------------------
__global__ __launch_bounds__(256) void softmax_kernel(
    const float* __restrict__ c, __bf16* __restrict__ w) {
  const int n = blockIdx.x;
  const int t = threadIdx.x;
  const int wv = t >> 6;
  const int lane = t & 63;
  const float* cb = c + (size_t)n * (BI * BO);
  __bf16* wb = w + (size_t)n * (BO * BI);

  for (int i = 0; i < 32; ++i) {
    const int o = wv * 32 + i;  // this wave's column
    float v0 = cb[lane * BO + o];
    float v1 = cb[(lane + 64) * BO + o];
    float mx = fmaxf(v0, v1);
#pragma unroll
    for (int d = 1; d < 64; d <<= 1) mx = fmaxf(mx, __shfl_xor(mx, d, 64));
    float e0 = __expf(v0 - mx);
    float e1 = __expf(v1 - mx);
    float s = e0 + e1;
#pragma unroll
    for (int d = 1; d < 64; d <<= 1) s += __shfl_xor(s, d, 64);
    float inv = 1.0f / s;
    wb[o * BI + lane] = (__bf16)(e0 * inv);
    wb[o * BI + lane + 64] = (__bf16)(e1 * inv);
  }
}

// ---------------------------------------------------------------------------
// Kernel 2: per-block GEMM [2048x128] @ [128x128], mfma_f32_32x32x16_bf16.
// WG = 256 threads (4 waves), output tile 128(M) x 128(O).
//  * x staged through LDS (coalesced 512B-row global reads -> bf16 ->
//    XOR-swizzled tile; this is the HBM->fragment transpose). 32KB.
//  * w B-fragments read directly from global: per instr, lane pairs
//    (l, l+32) form 32B segments at 256B stride across 32 rows of the
//    32KB w block -> L1/L2-resident (block reused by 16 WGs), latency
//    hidden by 3 WGs/CU. These loads don't depend on the barrier, so the
//    compiler can overlap them with x staging.
//  * Natural dispatch order: blockIdx.x (m-tile) fastest -> 16 consecutive
//    WGs share one n -> w locality is automatic. (R1's XCD swizzle removed:
//    unproven, and x/out have zero cross-WG reuse anyway.)
// ---------------------------------------------------------------------------
__global__ __launch_bounds__(256, 3) void gemm_kernel(
    const float* __restrict__ x, const __bf16* __restrict__ w,
    float* __restrict__ out) {
  __shared__ __align__(16) __bf16 xs[128 * 16 * 8];  // 32 KB, [m][chunk^swz][8]

  const int n = blockIdx.y;
  const int m_base = blockIdx.x * 128;
  const int t = threadIdx.x;
  const int wv = t >> 6;
  const int lane = t & 63;
  const int lr = lane & 31;
  const int half = lane >> 5;

  // ---- stage x tile: 128x128 fp32 -> bf16 (16 float4 loads per thread) ----
  // lin = t + i*256: 32 consecutive lanes cover one row's 512B contiguously.
  {
    const float* xg = x + (size_t)m_base * LAYER + n * BI;
#pragma unroll
    for (int i = 0; i < 16; ++i) {
      int lin = t + i * 256;          // float4 index within tile
      int m = lin >> 5;               // row
      int k4 = lin & 31;              // float4 col (k = 4*k4)
      float4 v = *(const float4*)(xg + (size_t)m * LAYER + k4 * 4);
      int chunk = (k4 >> 1) ^ (m & 15);
      bf16x4_t p;
      p[0] = (__bf16)v.x; p[1] = (__bf16)v.y;
      p[2] = (__bf16)v.z; p[3] = (__bf16)v.w;
      *(bf16x4_t*)&xs[(m * 16 + chunk) * 8 + (k4 & 1) * 4] = p;
    }
  }
  __syncthreads();

  floatx16_t acc[4];
#pragma unroll
  for (int nt = 0; nt < 4; ++nt)
#pragma unroll
    for (int r = 0; r < 16; ++r) acc[nt][r] = 0.0f;

  const int arow = wv * 32 + lr;  // A fragment row
  const __bf16* wg = w + (size_t)n * (BO * BI);

  // K = 128: 8 MFMA steps of k=16. A from swizzled LDS, B from global (hot).
#pragma unroll
  for (int step = 0; step < 8; ++step) {
    const int kc = step * 2 + half;  // 8-elem chunk index along K
    bf16x8_t a = *(const bf16x8_t*)&xs[(arow * 16 + (kc ^ (arow & 15))) * 8];
#pragma unroll
    for (int nt = 0; nt < 4; ++nt) {
      int ocol = nt * 32 + lr;       // B fragment col
      bf16x8_t b = *(const bf16x8_t*)(wg + ocol * BI + kc * 8);
      acc[nt] =
          __builtin_amdgcn_mfma_f32_32x32x16_bf16(a, b, acc[nt], 0, 0, 0);
    }
  }

  // ---- epilogue: measured C/D mapping col=lane&31, row=(r&3)+8*(r>>2)+4*half
  float* og = out + (size_t)(m_base + wv * 32) * LAYER + n * BO;
#pragma unroll
  for (int nt = 0; nt < 4; ++nt) {
#pragma unroll
    for (int r = 0; r < 16; ++r) {
      int row = (r & 3) + 8 * (r >> 2) + 4 * half;
      og[(size_t)row * LAYER + nt * 32 + lr] = acc[nt][r];
    }
  }
}

extern "C" void kernel_launch(void* const* d_in, const int* in_sizes, int n_in,
                              void* d_out, int out_size, void* d_ws,
                              size_t ws_size, hipStream_t stream) {
  const float* x = (const float*)d_in[0];   // [2048, 65536]
  const float* c = (const float*)d_in[1];   // [512, 128, 128]
  float* out = (float*)d_out;               // [2048, 65536]
  __bf16* w = (__bf16*)d_ws;                // [512, 128, 128] bf16, [n][o][m]

  softmax_kernel<<<dim3(N_BLOCKS), dim3(256), 0, stream>>>(c, w);
  gemm_kernel<<<dim3(BATCH / 128, N_BLOCKS), dim3(256), 0, stream>>>(x, w, out);
}